// Round 1
// baseline (21874.179 us; speedup 1.0000x reference)
//
#include <hip/hip_runtime.h>
#include <math.h>

#define DEVINL __device__ __forceinline__

// ---------------------------------------------------------------------------
// RSSM scan: B=32, T=64, DETER=2048, HID=1024, FLAT=1024, BLOCKS=8, DPB=256
// fp32 throughout (bf16 would flip argmaxes -> cascading recurrence error).
// 5 launches per step; K-split GEMMs write deterministic slabs; finalizer WGs
// (same launch, counter spin) reduce slabs, apply rms+silu, materialize
// activated inputs. Masking folded into 'determ' = m_t * deter_{t-1}.
// ---------------------------------------------------------------------------

struct RPtrs {
  const float *embed, *action; const int *is_first;
  const float *W_in_deter, *b_in_deter, *g_in_deter;
  const float *W_in_stoch, *b_in_stoch, *g_in_stoch;
  const float *W_in_act,   *b_in_act,   *g_in_act;
  const float *W_dyn, *b_dyn, *g_dyn;
  const float *W_gru, *b_gru;
  const float *W_p0, *b_p0, *g_p0;
  const float *W_p1, *b_p1, *g_p1;
  const float *W_po, *b_po;
  const float *W_q0, *b_q0, *g_q0;
  const float *W_qo, *b_qo;
  float *out_post, *out_prior, *out_deters;
  float *deter, *determ, *xact, *hact, *p0act, *q0act, *p1act, *x12pre;
  float *slabA, *slabB, *stoch_scale;
  int *sidxg; unsigned *ctr;
};

DEVINL void arrive(unsigned* c) {
  __threadfence();
  __syncthreads();
  if (threadIdx.x == 0)
    __hip_atomic_fetch_add(c, 1u, __ATOMIC_RELEASE, __HIP_MEMORY_SCOPE_AGENT);
}

DEVINL void waitc(const unsigned* c, unsigned target) {
  while (__hip_atomic_load(c, __ATOMIC_RELAXED, __HIP_MEMORY_SCOPE_AGENT) < target)
    __builtin_amdgcn_s_sleep(2);
  (void)__hip_atomic_load(c, __ATOMIC_ACQUIRE, __HIP_MEMORY_SCOPE_AGENT);
}

// ---- A-tile loaders --------------------------------------------------------
struct LdPlain {
  const float* A; int lda;
  DEVINL float operator()(int r, int k) const { return A[(size_t)r * lda + k]; }
};
struct LdDyn {   // per-block: [dg(256, masked deter) | x(3072, activated)]
  const float* dm; const float* x; int blk;
  DEVINL float operator()(int r, int k) const {
    return (k < 256) ? dm[r * 2048 + blk * 256 + k] : x[r * 3072 + (k - 256)];
  }
};
struct LdQ0 {    // [deter(2048) | embed(1024)]
  const float* det; const float* emb; int t;
  DEVINL float operator()(int r, int k) const {
    return (k < 2048) ? det[r * 2048 + k]
                      : emb[((size_t)r * 64 + t) * 1024 + (k - 2048)];
  }
};

// ---- generic skinny GEMM producer: one WG = 32 cols x 32 rows x K-chunk ----
// writes slab[r][scb+c] (plus bias if provided). KC multiple of 64.
template <typename LA>
DEVINL void gemm_tile(LA la, const float* __restrict__ W, int ldw, int wcb,
                      int k0, int KC, float* __restrict__ slabBase, int sst,
                      int scb, const float* __restrict__ bias) {
  __shared__ float Al[64][36];   // [k][r], padded: 16B-aligned rows, ok banks
  const int tid = threadIdx.x;
  const int c = tid & 31;
  const int r0 = (tid >> 5) * 4;
  float a0 = 0.f, a1 = 0.f, a2 = 0.f, a3 = 0.f;
  for (int kb = 0; kb < KC; kb += 64) {
    __syncthreads();
#pragma unroll
    for (int i = 0; i < 8; ++i) {
      int idx = tid + i * 256;
      int kk = idx & 63, rr = idx >> 6;
      Al[kk][rr] = la(rr, k0 + kb + kk);
    }
    __syncthreads();
    const float* Wp = W + (size_t)(k0 + kb) * ldw + wcb + c;
#pragma unroll 8
    for (int kk = 0; kk < 64; ++kk) {
      float w = Wp[(size_t)kk * ldw];
      float4 av = *(const float4*)(&Al[kk][r0]);
      a0 = fmaf(av.x, w, a0); a1 = fmaf(av.y, w, a1);
      a2 = fmaf(av.z, w, a2); a3 = fmaf(av.w, w, a3);
    }
  }
  if (bias) { float b = bias[wcb + c]; a0 += b; a1 += b; a2 += b; a3 += b; }
  float* s = slabBase + (size_t)r0 * sst + scb + c;
  s[0] = a0; s[sst] = a1; s[(size_t)2 * sst] = a2; s[(size_t)3 * sst] = a3;
}

// ---- finalizer: y = sum(slabs); scale = rsqrt(mean(y^2)+eps); out=silu(y*s*g)
DEVINL void finalize_act(const float* __restrict__ slab, int sst, int nchunk,
                         int r, int N, const float* __restrict__ g,
                         float* __restrict__ outrow, float invN) {
  __shared__ float red_[8];
  const int tid = threadIdx.x;
  float ss = 0.f;
  for (int c = tid; c < N; c += 256) {
    float y = 0.f;
#pragma unroll 4
    for (int kc = 0; kc < 4; ++kc)
      if (kc < nchunk) y += slab[((size_t)kc * 32 + r) * sst + c];
    ss += y * y;
  }
#pragma unroll
  for (int o = 32; o > 0; o >>= 1) ss += __shfl_down(ss, o, 64);
  if ((tid & 63) == 0) red_[tid >> 6] = ss;
  __syncthreads();
  if (tid == 0)
    red_[4] = 1.f / sqrtf((red_[0] + red_[1] + red_[2] + red_[3]) * invN + 1e-6f);
  __syncthreads();
  const float sc = red_[4];
  for (int c = tid; c < N; c += 256) {
    float y = 0.f;
#pragma unroll 4
    for (int kc = 0; kc < 4; ++kc)
      if (kc < nchunk) y += slab[((size_t)kc * 32 + r) * sst + c];
    float v = y * sc * g[c];
    outrow[c] = v / (1.f + expf(-v));
  }
  __syncthreads();
}

// ---- x1 (stoch gather) + x2 (action) producer ------------------------------
DEVINL void x12_body(const RPtrs& p, int t, int b8) {
  __shared__ float sW2[16][128];
  __shared__ float sa[32][16];
  __shared__ float scoef[32];
  __shared__ int sidx[32][32];
  const int tid = threadIdx.x;
  const int cb = b8 * 128;
  for (int i = tid; i < 1024; i += 256) sidx[i >> 5][i & 31] = p.sidxg[i] & 31;
  for (int i = tid; i < 512; i += 256) {
    int r = i >> 4, ii = i & 15;
    float m = p.is_first[r * 64 + t] ? 0.f : 1.f;
    float v = p.action[((size_t)r * 64 + t) * 16 + ii] * m;
    sa[r][ii] = v / fmaxf(fabsf(v), 1.f);
  }
  if (tid < 32) {
    float m = p.is_first[tid * 64 + t] ? 0.f : 1.f;
    scoef[tid] = m * p.stoch_scale[tid];
  }
  for (int i = tid; i < 2048; i += 256) {
    int ii = i >> 7, c = i & 127;
    sW2[ii][c] = p.W_in_act[ii * 1024 + cb + c];
  }
  __syncthreads();
  const int c = tid & 127;
  for (int r = tid >> 7; r < 32; r += 2) {
    float coef = scoef[r];
    float s1 = 0.f;
    if (coef != 0.f) {
#pragma unroll
      for (int gg = 0; gg < 32; ++gg)
        s1 += p.W_in_stoch[((size_t)(gg * 32 + sidx[r][gg])) * 1024 + cb + c];
    }
    p.x12pre[(size_t)r * 1024 + cb + c] = p.b_in_stoch[cb + c] + coef * s1;
    float s2 = p.b_in_act[cb + c];
#pragma unroll
    for (int ii = 0; ii < 16; ++ii) s2 = fmaf(sa[r][ii], sW2[ii][c], s2);
    p.x12pre[32768 + (size_t)r * 1024 + cb + c] = s2;
  }
}

// ---- prior-output finalizer (sum slabs -> d_out) ---------------------------
DEVINL void pof_body(const RPtrs& p, int tpo, int fid) {
  const int tid = threadIdx.x;
  for (int rr = 0; rr < 4; ++rr) {
    int r = fid * 4 + rr;
    for (int c = tid; c < 1024; c += 256) {
      float y = 0.f;
#pragma unroll
      for (int kc = 0; kc < 4; ++kc) y += p.slabB[((size_t)kc * 32 + r) * 1024 + c];
      p.out_prior[((size_t)r * 64 + tpo) * 1024 + c] = y;
    }
  }
}

// ---- post-output finalizer: write logits + argmax -> stoch idx -------------
DEVINL void qof_body(const RPtrs& p, int t, int fid) {
  __shared__ float yr[1024];
  const int tid = threadIdx.x;
  for (int rr = 0; rr < 4; ++rr) {
    int r = fid * 4 + rr;
    for (int c = tid; c < 1024; c += 256) {
      float y = 0.f;
#pragma unroll
      for (int kc = 0; kc < 4; ++kc) y += p.slabB[((size_t)kc * 32 + r) * 1024 + c];
      yr[c] = y;
      p.out_post[((size_t)r * 64 + t) * 1024 + c] = y;
    }
    __syncthreads();
    if (tid < 32) {
      int base = tid * 32;
      float best = yr[base]; int bi = 0;
      for (int c2 = 1; c2 < 32; ++c2) {
        float v = yr[base + c2];
        if (v > best) { best = v; bi = c2; }   // strict > keeps first index
      }
      p.sidxg[r * 32 + tid] = bi;
    }
    if (tid == 0) p.stoch_scale[r] = 1.f;
    __syncthreads();
  }
}

// ===========================================================================

__global__ __launch_bounds__(256) void rssm_Z0(RPtrs p) {
  size_t i = (size_t)blockIdx.x * 256 + threadIdx.x;
  for (size_t j = i; j < 65536; j += (size_t)gridDim.x * 256) {
    p.deter[j] = 0.f; p.determ[j] = 0.f;
  }
  if (i < 1024) p.sidxg[i] = 0;
  if (i < 32) p.stoch_scale[i] = 0.f;
  if (i < 16) p.ctr[i] = 0u;
}

// L1: x0 GEMM | po(t-1) GEMM | x1x2 | finalizers
__global__ __launch_bounds__(256) void rssm_L1(RPtrs p, int t) {
  int wg = blockIdx.x;
  if (wg < 128) {                 // x0: (m*deter) @ W_in_deter  (mask in determ)
    int nch = wg & 31, kc = wg >> 5;
    LdPlain la{p.determ, 2048};
    gemm_tile(la, p.W_in_deter, 1024, nch * 32, kc * 512, 512,
              p.slabA + (size_t)kc * 32 * 2048, 2048, nch * 32,
              kc == 0 ? p.b_in_deter : nullptr);
    arrive(p.ctr + 0);
  } else if (wg < 256) {          // po for step t-1
    if (t == 0) return;
    int i = wg - 128, nch = i & 31, kc = i >> 5;
    LdPlain la{p.p1act, 1024};
    gemm_tile(la, p.W_po, 1024, nch * 32, kc * 256, 256,
              p.slabB + (size_t)kc * 32 * 1024, 1024, nch * 32,
              kc == 0 ? p.b_po : nullptr);
    arrive(p.ctr + 7);
  } else if (wg < 264) {          // x1 gather + x2
    x12_body(p, t, wg - 256);
    arrive(p.ctr + 1);
  } else if (wg < 272) {          // x0 finalizer -> xact[:,0:1024]
    waitc(p.ctr + 0, 128u * (unsigned)(t + 1));
    int fid = wg - 264;
    for (int rr = 0; rr < 4; ++rr) {
      int r = fid * 4 + rr;
      finalize_act(p.slabA, 2048, 4, r, 1024, p.g_in_deter,
                   p.xact + (size_t)r * 3072, 1.f / 1024.f);
    }
  } else if (wg < 280) {          // x1/x2 finalizer -> xact[:,1024:3072]
    waitc(p.ctr + 1, 8u * (unsigned)(t + 1));
    int fid = wg - 272;
    for (int rr = 0; rr < 4; ++rr) {
      int r = fid * 4 + rr;
      finalize_act(p.x12pre, 1024, 1, r, 1024, p.g_in_stoch,
                   p.xact + (size_t)r * 3072 + 1024, 1.f / 1024.f);
      finalize_act(p.x12pre + 32768, 1024, 1, r, 1024, p.g_in_act,
                   p.xact + (size_t)r * 3072 + 2048, 1.f / 1024.f);
    }
  } else {                        // po finalizer (t-1) -> d_out prior
    if (t == 0) return;
    waitc(p.ctr + 7, 128u * (unsigned)t);
    pof_body(p, t - 1, wg - 280);
  }
}

// L2: block-linear dyn GEMM + finalizer -> hact
__global__ __launch_bounds__(256) void rssm_L2(RPtrs p, int t) {
  int wg = blockIdx.x;
  if (wg < 256) {
    int blk = wg >> 5, i = wg & 31, nch = i & 7, kc = i >> 3;
    LdDyn la{p.determ, p.xact, blk};
    gemm_tile(la, p.W_dyn + (size_t)blk * 3328 * 256, 256, nch * 32,
              kc * 832, 832, p.slabA + (size_t)kc * 32 * 2048, 2048,
              blk * 256 + nch * 32, kc == 0 ? p.b_dyn + blk * 256 : nullptr);
    arrive(p.ctr + 2);
  } else {
    waitc(p.ctr + 2, 256u * (unsigned)(t + 1));
    int fid = wg - 256;
    for (int rr = 0; rr < 4; ++rr) {
      int r = fid * 4 + rr;
      finalize_act(p.slabA, 2048, 4, r, 2048, p.g_dyn,
                   p.hact + (size_t)r * 2048, 1.f / 2048.f);
    }
  }
}

// L3: GRU gates + state update; writes deter, determ(t+1), d_out deters
__global__ __launch_bounds__(256) void rssm_L3(RPtrs p, int t) {
  int wg = blockIdx.x;
  int blk = wg >> 4, jch = wg & 15;
  int jbase = jch * 16;
  __shared__ float Al[256][34];
  const int tid = threadIdx.x;
  for (int i = tid; i < 256 * 32; i += 256) {
    int kk = i & 255, rr = i >> 8;
    Al[kk][rr] = p.hact[(size_t)rr * 2048 + blk * 256 + kk];
  }
  __syncthreads();
  const int j = tid & 15, rg = tid >> 4;
  const int r0 = rg * 2;
  const int jcol = jbase + j;
  const float* Wg = p.W_gru + (size_t)blk * 256 * 768;
  float r0a = 0, r1a = 0, c0a = 0, c1a = 0, u0a = 0, u1a = 0;
#pragma unroll 4
  for (int kk = 0; kk < 256; ++kk) {
    float wr = Wg[(size_t)kk * 768 + jcol];
    float wc = Wg[(size_t)kk * 768 + 256 + jcol];
    float wu = Wg[(size_t)kk * 768 + 512 + jcol];
    float2 av = *(const float2*)(&Al[kk][r0]);
    r0a = fmaf(av.x, wr, r0a); r1a = fmaf(av.y, wr, r1a);
    c0a = fmaf(av.x, wc, c0a); c1a = fmaf(av.y, wc, c1a);
    u0a = fmaf(av.x, wu, u0a); u1a = fmaf(av.y, wu, u1a);
  }
  const int col = blk * 256 + jcol;
  const float br = p.b_gru[blk * 768 + jcol];
  const float bc = p.b_gru[blk * 768 + 256 + jcol];
  const float bu = p.b_gru[blk * 768 + 512 + jcol];
#pragma unroll
  for (int rr = 0; rr < 2; ++rr) {
    int r = r0 + rr;
    float gr = (rr ? r1a : r0a) + br;
    float gc = (rr ? c1a : c0a) + bc;
    float gu = (rr ? u1a : u0a) + bu;
    float rs = 1.f / (1.f + expf(-gr));
    float cc = tanhf(rs * gc);
    float uu = 1.f / (1.f + expf(-(gu - 1.f)));
    float dg = p.determ[(size_t)r * 2048 + col];
    float nd = uu * cc + (1.f - uu) * dg;
    p.deter[(size_t)r * 2048 + col] = nd;
    p.out_deters[((size_t)r * 64 + t) * 2048 + col] = nd;
    float mn = 0.f;
    if (t + 1 < 64) mn = p.is_first[r * 64 + (t + 1)] ? 0.f : 1.f;
    p.determ[(size_t)r * 2048 + col] = nd * mn;
  }
}

// L4: p0 GEMM | q0 GEMM | finalizers -> p0act, q0act
__global__ __launch_bounds__(256) void rssm_L4(RPtrs p, int t) {
  int wg = blockIdx.x;
  if (wg < 128) {
    int nch = wg & 31, kc = wg >> 5;
    LdPlain la{p.deter, 2048};
    gemm_tile(la, p.W_p0, 1024, nch * 32, kc * 512, 512,
              p.slabA + (size_t)kc * 32 * 2048, 2048, nch * 32,
              kc == 0 ? p.b_p0 : nullptr);
    arrive(p.ctr + 3);
  } else if (wg < 256) {
    int i = wg - 128, nch = i & 31, kc = i >> 5;
    LdQ0 la{p.deter, p.embed, t};
    gemm_tile(la, p.W_q0, 1024, nch * 32, kc * 768, 768,
              p.slabB + (size_t)kc * 32 * 1024, 1024, nch * 32,
              kc == 0 ? p.b_q0 : nullptr);
    arrive(p.ctr + 4);
  } else if (wg < 264) {
    waitc(p.ctr + 3, 128u * (unsigned)(t + 1));
    int fid = wg - 256;
    for (int rr = 0; rr < 4; ++rr) {
      int r = fid * 4 + rr;
      finalize_act(p.slabA, 2048, 4, r, 1024, p.g_p0,
                   p.p0act + (size_t)r * 1024, 1.f / 1024.f);
    }
  } else {
    waitc(p.ctr + 4, 128u * (unsigned)(t + 1));
    int fid = wg - 264;
    for (int rr = 0; rr < 4; ++rr) {
      int r = fid * 4 + rr;
      finalize_act(p.slabB, 1024, 4, r, 1024, p.g_q0,
                   p.q0act + (size_t)r * 1024, 1.f / 1024.f);
    }
  }
}

// L5: p1 GEMM | qo GEMM | p1 finalizer -> p1act | qo finalizer -> out+argmax
__global__ __launch_bounds__(256) void rssm_L5(RPtrs p, int t) {
  int wg = blockIdx.x;
  if (wg < 128) {
    int nch = wg & 31, kc = wg >> 5;
    LdPlain la{p.p0act, 1024};
    gemm_tile(la, p.W_p1, 1024, nch * 32, kc * 256, 256,
              p.slabA + (size_t)kc * 32 * 2048, 2048, nch * 32,
              kc == 0 ? p.b_p1 : nullptr);
    arrive(p.ctr + 5);
  } else if (wg < 256) {
    int i = wg - 128, nch = i & 31, kc = i >> 5;
    LdPlain la{p.q0act, 1024};
    gemm_tile(la, p.W_qo, 1024, nch * 32, kc * 256, 256,
              p.slabB + (size_t)kc * 32 * 1024, 1024, nch * 32,
              kc == 0 ? p.b_qo : nullptr);
    arrive(p.ctr + 6);
  } else if (wg < 264) {
    waitc(p.ctr + 5, 128u * (unsigned)(t + 1));
    int fid = wg - 256;
    for (int rr = 0; rr < 4; ++rr) {
      int r = fid * 4 + rr;
      finalize_act(p.slabA, 2048, 4, r, 1024, p.g_p1,
                   p.p1act + (size_t)r * 1024, 1.f / 1024.f);
    }
  } else {
    waitc(p.ctr + 6, 128u * (unsigned)(t + 1));
    qof_body(p, t, wg - 264);
  }
}

// final po for t=63
__global__ __launch_bounds__(256) void rssm_PO(RPtrs p) {
  int wg = blockIdx.x;
  if (wg < 128) {
    int nch = wg & 31, kc = wg >> 5;
    LdPlain la{p.p1act, 1024};
    gemm_tile(la, p.W_po, 1024, nch * 32, kc * 256, 256,
              p.slabB + (size_t)kc * 32 * 1024, 1024, nch * 32,
              kc == 0 ? p.b_po : nullptr);
    arrive(p.ctr + 7);
  } else {
    waitc(p.ctr + 7, 128u * 64u);
    pof_body(p, 63, wg - 128);
  }
}

// ===========================================================================
extern "C" void kernel_launch(void* const* d_in, const int* in_sizes, int n_in,
                              void* d_out, int out_size, void* d_ws,
                              size_t ws_size, hipStream_t stream) {
  RPtrs p;
  p.embed      = (const float*)d_in[0];
  p.action     = (const float*)d_in[1];
  p.is_first   = (const int*)d_in[2];
  p.W_in_deter = (const float*)d_in[3];  p.b_in_deter = (const float*)d_in[4];  p.g_in_deter = (const float*)d_in[5];
  p.W_in_stoch = (const float*)d_in[6];  p.b_in_stoch = (const float*)d_in[7];  p.g_in_stoch = (const float*)d_in[8];
  p.W_in_act   = (const float*)d_in[9];  p.b_in_act   = (const float*)d_in[10]; p.g_in_act   = (const float*)d_in[11];
  p.W_dyn      = (const float*)d_in[12]; p.b_dyn      = (const float*)d_in[13]; p.g_dyn      = (const float*)d_in[14];
  p.W_gru      = (const float*)d_in[15]; p.b_gru      = (const float*)d_in[16];
  p.W_p0       = (const float*)d_in[17]; p.b_p0       = (const float*)d_in[18]; p.g_p0       = (const float*)d_in[19];
  p.W_p1       = (const float*)d_in[20]; p.b_p1       = (const float*)d_in[21]; p.g_p1       = (const float*)d_in[22];
  p.W_po       = (const float*)d_in[23]; p.b_po       = (const float*)d_in[24];
  p.W_q0       = (const float*)d_in[25]; p.b_q0       = (const float*)d_in[26]; p.g_q0       = (const float*)d_in[27];
  p.W_qo       = (const float*)d_in[28]; p.b_qo       = (const float*)d_in[29];

  float* o = (float*)d_out;
  p.out_post   = o;               // [32][64][1024]
  p.out_prior  = o + 2097152;     // [32][64][1024]
  p.out_deters = o + 4194304;     // [32][64][2048]

  float* w = (float*)d_ws;
  p.deter  = w;             // 65536
  p.determ = w + 65536;     // 65536
  p.xact   = w + 131072;    // 98304  [32][3072]
  p.hact   = w + 229376;    // 65536
  p.p0act  = w + 294912;    // 32768
  p.q0act  = w + 327680;    // 32768
  p.p1act  = w + 360448;    // 32768
  p.x12pre = w + 393216;    // 65536  [2][32][1024]
  p.slabA  = w + 458752;    // 262144 [4][32][2048]
  p.slabB  = w + 720896;    // 131072 [4][32][1024]
  p.stoch_scale = w + 851968;             // 32
  p.sidxg  = (int*)(w + 852000);          // 1024
  p.ctr    = (unsigned*)(w + 853024);     // 16

  rssm_Z0<<<64, 256, 0, stream>>>(p);
  for (int t = 0; t < 64; ++t) {
    rssm_L1<<<288, 256, 0, stream>>>(p, t);
    rssm_L2<<<264, 256, 0, stream>>>(p, t);
    rssm_L3<<<128, 256, 0, stream>>>(p, t);
    rssm_L4<<<272, 256, 0, stream>>>(p, t);
    rssm_L5<<<272, 256, 0, stream>>>(p, t);
  }
  rssm_PO<<<136, 256, 0, stream>>>(p);
}